// Round 18
// baseline (150.250 us; speedup 1.0000x reference)
//
#include <hip/hip_runtime.h>
#include <hip/hip_bf16.h>

using bf16 = __hip_bfloat16;
typedef __attribute__((ext_vector_type(8))) short bf16x8;
typedef __attribute__((ext_vector_type(4))) short bf16x4;
typedef __attribute__((ext_vector_type(4))) float f32x4;
typedef __attribute__((ext_vector_type(16))) float f32x16;

static constexpr int Bb = 4, Ss = 2048, Dd = 1024, Hh = 16, HD = 64;
static constexpr int TD = 3 * Dd;            // 3072
static constexpr int Mrows = Bb * Ss;        // 8192

#define MFMA16(a, b, c) __builtin_amdgcn_mfma_f32_16x16x32_bf16((a), (b), (c), 0, 0, 0)
#define MFMA32(a, b, c) __builtin_amdgcn_mfma_f32_32x32x16_bf16((a), (b), (c), 0, 0, 0)

__device__ __forceinline__ void gload_lds16(const void* g, void* l) {
    __builtin_amdgcn_global_load_lds(
        (const __attribute__((address_space(1))) void*)g,
        (__attribute__((address_space(3))) void*)l, 16, 0, 0);
}

__device__ __forceinline__ unsigned lds_addr(const void* p) {
    return (unsigned)(unsigned long long)(const __attribute__((address_space(3))) char*)p;
}

__device__ __forceinline__ unsigned pack2bf(float a, float b) {
    bf16 x = __float2bfloat16(a), y = __float2bfloat16(b);
    return (unsigned)(*(unsigned short*)&x) | ((unsigned)(*(unsigned short*)&y) << 16);
}

__device__ __forceinline__ float bf2f(short s) {
    unsigned u = ((unsigned)(unsigned short)s) << 16;
    return __builtin_bit_cast(float, u);
}

// ---------------- fused cast fp32 -> bf16 (x, Wqkv, Wo in one launch) ------
__global__ void cast_all(const float* __restrict__ x, const float* __restrict__ w1,
                         const float* __restrict__ w2, bf16* __restrict__ xb,
                         bf16* __restrict__ w1b, bf16* __restrict__ w2b) {
    int i = blockIdx.x * blockDim.x + threadIdx.x;   // 4-elem groups
    const float* src; bf16* dst; int off;
    if (i < 2097152)      { src = x;  dst = xb;  off = i; }
    else if (i < 2883584) { src = w1; dst = w1b; off = i - 2097152; }
    else                  { src = w2; dst = w2b; off = i - 2883584; }
    float4 v = ((const float4*)src)[off];
    uint2 o;
    o.x = pack2bf(v.x, v.y);
    o.y = pack2bf(v.z, v.w);
    *(uint2*)(dst + 4l * off) = o;
}

// ---------------- GEMM: C[m,n] = sum_k A[m,k] * Bt[n,k] ----------------
// r14 proven win: 128x128 tile, BK=64, XOR-swizzled LDS (128B rows),
// simple 2-barrier loop, 32KB LDS, (256,4). UNCHANGED.
template<bool OUT_BF16>
__global__ __launch_bounds__(256, 4) void gemm_bt(
    const bf16* __restrict__ A, const bf16* __restrict__ Bt,
    bf16* __restrict__ Cb, float* __restrict__ Cf, const float* __restrict__ bias,
    int M, int N, int K)
{
    __shared__ __align__(16) bf16 As[128 * 64];   // 16 KB
    __shared__ __align__(16) bf16 Bs[128 * 64];   // 16 KB
    const int tid = threadIdx.x;
    const int lane = tid & 63, wid = tid >> 6;
    const int lc = lane & 15, lg = lane >> 4;
    const int wr = wid >> 1, wc = wid & 1;

    const int nwg = gridDim.x * gridDim.y;
    int orig = blockIdx.y * gridDim.x + blockIdx.x;
    int swz = orig;
    if ((nwg & 7) == 0) swz = (orig & 7) * (nwg >> 3) + (orig >> 3);
    const long tile_m = (long)(swz / (int)gridDim.x) * 128;
    const long tile_n = (long)(swz % (int)gridDim.x) * 128;

    const f32x4 fz = {0.f, 0.f, 0.f, 0.f};
    f32x4 acc[4][4];
#pragma unroll
    for (int i = 0; i < 4; ++i)
#pragma unroll
        for (int j = 0; j < 4; ++j) acc[i][j] = fz;

    for (int k0 = 0; k0 < K; k0 += 64) {
#pragma unroll
        for (int it = 0; it < 4; ++it) {
            int s = tid + it * 256;
            int r = s >> 3;
            int cs = (s & 7) ^ (r & 7);
            gload_lds16(A  + (tile_m + r) * (long)K + k0 + cs * 8, (char*)As + s * 16);
            gload_lds16(Bt + (tile_n + r) * (long)K + k0 + cs * 8, (char*)Bs + s * 16);
        }
        __syncthreads();
#pragma unroll
        for (int ks = 0; ks < 2; ++ks) {
            bf16x8 af[4], bfr[4];
#pragma unroll
            for (int i = 0; i < 4; ++i) {
                int rowa = wr * 64 + i * 16 + lc;
                af[i] = *(const bf16x8*)((const char*)As +
                        ((rowa * 128 + ks * 64 + lg * 16) ^ ((rowa & 7) << 4)));
                int rowb = wc * 64 + i * 16 + lc;
                bfr[i] = *(const bf16x8*)((const char*)Bs +
                        ((rowb * 128 + ks * 64 + lg * 16) ^ ((rowb & 7) << 4)));
            }
#pragma unroll
            for (int i = 0; i < 4; ++i)
#pragma unroll
                for (int j = 0; j < 4; ++j)
                    acc[i][j] = MFMA16(af[i], bfr[j], acc[i][j]);
        }
        __syncthreads();
    }
#pragma unroll
    for (int i = 0; i < 4; ++i)
#pragma unroll
        for (int j = 0; j < 4; ++j)
#pragma unroll
            for (int r = 0; r < 4; ++r) {
                long row = tile_m + wr * 64 + i * 16 + lg * 4 + r;
                long col = tile_n + wc * 64 + j * 16 + lc;
                float v = acc[i][j][r];
                if constexpr (OUT_BF16) Cb[row * N + col] = __float2bfloat16(v);
                else                    Cf[row * N + col] = v + bias[col];
            }
}

// ---------------- causal flash attention v10: heavy strips kv-split --------
// v8 TILE body verbatim. Blocks: y<16 -> heavy strip s=8+(y>>1), kv half
// (y&1) of nt=2s+2 tiles (s+1 = 9..16 tiles, partial output); y>=16 ->
// light strip s=23-y full range (direct output). 1536 blocks ~ 1.2x the
// ~5-block/CU residency capacity -> real backfill, max work unit 16 tiles
// (was 32). Heavy halves write O/l + (m2,l) partials; attn_combine merges.
__global__ __launch_bounds__(256, 2) void attn_fwd10(const bf16* __restrict__ qkv,
                                                     bf16* __restrict__ O0,
                                                     bf16* __restrict__ O1,
                                                     float2* __restrict__ mlb) {
    const int bh = blockIdx.x;                 // 0..63
    const int y  = blockIdx.y;                 // 0..23
    const int b = bh >> 4, h = bh & 15;
    const int tid = threadIdx.x;
    const int lane = tid & 63, wid = tid >> 6;
    const int ln31 = lane & 31, hi = lane >> 5;
    const int ch = (lane >> 4) & 1, c16 = lane & 15;
    const long rowbase = (long)b * Ss;
    const float CL2 = 0.18033688f;             // 0.125 * log2(e)

    int s, kb, ke, half;
    bool partial;
    if (y < 16) {                              // heavy halves, biggest first
        s = 15 - (y >> 1);                     // 15..8
        half = y & 1;
        const int hsz = s + 1;                 // tiles per half
        kb = half * hsz;
        ke = kb + hsz;
        partial = true;
    } else {                                   // light strips, descending
        s = 23 - y;                            // 7..0
        half = 0;
        kb = 0;
        ke = 2 * s + 2;
        partial = false;
    }
    const int q0 = s * 128 + wid * 32;

    __shared__ __align__(16) bf16 Ks[2][64 * 64];
    __shared__ __align__(16) bf16 Vs[2][64 * 64];

    const int sK0 = tid, sK1 = tid + 256;
    const int rK0 = sK0 >> 3, cK0 = ((sK0 & 7) ^ (rK0 & 7)) * 8;
    const int rK1 = sK1 >> 3, cK1 = ((sK1 & 7) ^ (rK1 & 7)) * 8;
    const int rV0 = ((sK0 >> 5) << 2) | ((sK0 >> 1) & 3);
    const int cV0 = ((((sK0 >> 3) & 3) << 1) | (sK0 & 1)) * 8;
    const int rV1 = ((sK1 >> 5) << 2) | ((sK1 >> 1) & 3);
    const int cV1 = ((((sK1 >> 3) & 3) << 1) | (sK1 & 1)) * 8;
    const bf16* gK0 = qkv + (rowbase + rK0) * (long)TD + h * HD + Dd + cK0;
    const bf16* gK1 = qkv + (rowbase + rK1) * (long)TD + h * HD + Dd + cK1;
    const bf16* gV0 = qkv + (rowbase + rV0) * (long)TD + h * HD + 2 * Dd + cV0;
    const bf16* gV1 = qkv + (rowbase + rV1) * (long)TD + h * HD + 2 * Dd + cV1;

    auto STAGE = [&](int buf, int kt) {
        const long o = (long)kt * 64 * TD;
        gload_lds16(gK0 + o, (char*)Ks[buf] + tid * 16);
        gload_lds16(gK1 + o, (char*)Ks[buf] + 4096 + tid * 16);
        gload_lds16(gV0 + o, (char*)Vs[buf] + tid * 16);
        gload_lds16(gV1 + o, (char*)Vs[buf] + 4096 + tid * 16);
    };

    bf16x8 qa[4];
#pragma unroll
    for (int dk = 0; dk < 4; ++dk)
        qa[dk] = *(const bf16x8*)(qkv + (rowbase + q0 + ln31) * (long)TD + h * HD + dk * 16 + hi * 8);

    f32x16 acc[2];
#pragma unroll
    for (int dt = 0; dt < 2; ++dt) acc[dt] = (f32x16)0.0f;
    float m2 = -3.0e38f;
    float l = 0.f;

    STAGE(0, kb);
    __syncthreads();

#pragma unroll 1
    for (int kt = kb; kt < ke; ++kt) {
        const int cur = (kt - kb) & 1;
        if (kt + 1 < ke) STAGE(cur ^ 1, kt + 1);

        if (kt * 64 <= q0 + 31) {
            const char* kbp = (const char*)Ks[cur];
            const char* vbp = (const char*)Vs[cur];
            f32x16 sc[2];
            __builtin_amdgcn_s_setprio(1);
#pragma unroll
            for (int st = 0; st < 2; ++st) {
                f32x16 z = (f32x16)0.0f;
                const int row = st * 32 + ln31;
                const int sw = (row & 7) << 4;
#pragma unroll
                for (int dk = 0; dk < 4; ++dk) {
                    bf16x8 ka = *(const bf16x8*)(kbp + ((row * 128 + dk * 32 + hi * 16) ^ sw));
                    z = MFMA32(ka, qa[dk], z);
                }
                sc[st] = z;
            }
            __builtin_amdgcn_s_setprio(0);
            if (kt * 64 + 63 > q0) {
                const int qg = q0 + ln31;
                const int kbase = kt * 64 + 4 * hi;
#pragma unroll
                for (int st = 0; st < 2; ++st)
#pragma unroll
                    for (int r = 0; r < 16; ++r) {
                        int kg = kbase + st * 32 + (r & 3) + 8 * (r >> 2);
                        if (kg > qg) sc[st][r] = -3.0e38f;
                    }
            }
            // ---- row max: depth-5 pairwise tree ----
            float mt16[16];
#pragma unroll
            for (int r = 0; r < 16; ++r) mt16[r] = fmaxf(sc[0][r], sc[1][r]);
#pragma unroll
            for (int off = 8; off; off >>= 1)
#pragma unroll
                for (int r = 0; r < off; ++r) mt16[r] = fmaxf(mt16[r], mt16[r + off]);
            float mx = fmaxf(mt16[0], __shfl_xor(mt16[0], 32));
            float pmax2 = mx * CL2;
            if (__ballot(pmax2 > m2 + 8.0f)) {
                float mnew = fmaxf(m2, pmax2);
                float sf = __builtin_amdgcn_exp2f(m2 - mnew);
                m2 = mnew;
                l *= sf;
#pragma unroll
                for (int r = 0; r < 16; ++r) {
                    float sfr = __shfl(sf, (r & 3) + 8 * (r >> 2) + 4 * hi);
                    acc[0][r] *= sfr;
                    acc[1][r] *= sfr;
                }
            }
            // ---- 16 V tr-reads early (literal offsets) ----
            bf16x4 vl[4][2], vh[4][2];
            const unsigned vbase = lds_addr(vbp) + hi * 1024 + ch * 128 + c16 * 8;
#define TRRD(L, H, O1, O2) \
            asm volatile("ds_read_b64_tr_b16 %0, %2 offset:" O1 "\n\t" \
                         "ds_read_b64_tr_b16 %1, %2 offset:" O2 \
                         : "=v"(L), "=v"(H) : "v"(vbase) : "memory");
            TRRD(vl[0][0], vh[0][0], "0",    "512")
            TRRD(vl[0][1], vh[0][1], "256",  "768")
            TRRD(vl[1][0], vh[1][0], "2048", "2560")
            TRRD(vl[1][1], vh[1][1], "2304", "2816")
            TRRD(vl[2][0], vh[2][0], "4096", "4608")
            TRRD(vl[2][1], vh[2][1], "4352", "4864")
            TRRD(vl[3][0], vh[3][0], "6144", "6656")
            TRRD(vl[3][1], vh[3][1], "6400", "6912")
#undef TRRD
            // ---- exp + 4-way partial sums + hw cvt_pk pack ----
            const float mt = m2;
            float s4[4] = {0.f, 0.f, 0.f, 0.f};
            unsigned w[2][8];
#pragma unroll
            for (int st = 0; st < 2; ++st)
#pragma unroll
                for (int n = 0; n < 8; ++n) {
                    float e0 = __builtin_amdgcn_exp2f(fmaf(sc[st][2 * n],     CL2, -mt));
                    float e1 = __builtin_amdgcn_exp2f(fmaf(sc[st][2 * n + 1], CL2, -mt));
                    s4[n & 3] += e0 + e1;
                    asm("v_cvt_pk_bf16_f32 %0, %1, %2"
                        : "=v"(w[st][n]) : "v"(e0), "v"(e1));
                }
            float sum = (s4[0] + s4[1]) + (s4[2] + s4[3]);
            sum += __shfl_xor(sum, 32);
            l += sum;
            // ---- P exchange: 8 permlane32_swap ----
            union { unsigned u[4]; bf16x8 v; } pa[4];
#pragma unroll
            for (int ksg = 0; ksg < 4; ++ksg) {
                const int st = ksg >> 1, kl = ksg & 1;
                unsigned x0 = w[st][4 * kl],     y0 = w[st][4 * kl + 2];
                unsigned x1 = w[st][4 * kl + 1], y1 = w[st][4 * kl + 3];
                asm volatile("v_permlane32_swap_b32 %0, %1" : "+v"(x0), "+v"(y0));
                asm volatile("v_permlane32_swap_b32 %0, %1" : "+v"(x1), "+v"(y1));
                pa[ksg].u[0] = x0; pa[ksg].u[1] = x1; pa[ksg].u[2] = y0; pa[ksg].u[3] = y1;
            }
            // ---- PV ----
            asm volatile("s_waitcnt lgkmcnt(0)" ::: "memory");
            __builtin_amdgcn_sched_barrier(0);
            __builtin_amdgcn_s_setprio(1);
#pragma unroll
            for (int ksg = 0; ksg < 4; ++ksg)
#pragma unroll
                for (int dt = 0; dt < 2; ++dt) {
                    bf16x8 vb = __builtin_shufflevector(vl[ksg][dt], vh[ksg][dt],
                                                        0, 1, 2, 3, 4, 5, 6, 7);
                    acc[dt] = MFMA32(pa[ksg].v, vb, acc[dt]);
                }
            __builtin_amdgcn_s_setprio(0);
        }

        __syncthreads();
    }

    // ---- epilogue: normalize; partial halves also record (m2, l) ----
    bf16* Op = (partial && half) ? O1 : O0;
    float invl = (l > 0.f) ? 1.f / l : 0.f;
#pragma unroll
    for (int r = 0; r < 16; ++r) {
        float ir = __shfl(invl, (r & 3) + 8 * (r >> 2) + 4 * hi);
        long orow = rowbase + q0 + (r & 3) + 8 * (r >> 2) + 4 * hi;
#pragma unroll
        for (int dt = 0; dt < 2; ++dt)
            Op[orow * Dd + h * HD + dt * 32 + ln31] = __float2bfloat16(acc[dt][r] * ir);
    }
    if (partial && hi == 0)
        mlb[((long)half * Mrows + rowbase + q0 + ln31) * Hh + h] = make_float2(m2, l);
}

// ---------------- combine heavy-strip partials (rows 1024..2047 of each seq)
__global__ void attn_combine(const bf16* __restrict__ O1,
                             const float2* __restrict__ mlb,
                             bf16* __restrict__ O0out) {
    int g = blockIdx.x * blockDim.x + threadIdx.x;   // 4096 rows x 128 groups
    int rp = g >> 7, c8 = g & 127;
    int b = rp >> 10;
    long row = (long)b * Ss + 1024 + (rp & 1023);
    int h = c8 >> 3;
    float2 a0 = mlb[row * Hh + h];
    float2 a1 = mlb[((long)Mrows + row) * Hh + h];
    float M = fmaxf(a0.x, a1.x);
    float w0 = a0.y * __builtin_amdgcn_exp2f(a0.x - M);
    float w1 = a1.y * __builtin_amdgcn_exp2f(a1.x - M);
    float inv = 1.f / (w0 + w1);
    w0 *= inv; w1 *= inv;
    long off = row * Dd + (long)c8 * 8;
    bf16x8 v0 = *(const bf16x8*)(O0out + off);
    bf16x8 v1 = *(const bf16x8*)(O1 + off);
    unsigned res[4];
#pragma unroll
    for (int i = 0; i < 4; ++i) {
        float o0 = w0 * bf2f(v0[2 * i])     + w1 * bf2f(v1[2 * i]);
        float o1 = w0 * bf2f(v0[2 * i + 1]) + w1 * bf2f(v1[2 * i + 1]);
        res[i] = pack2bf(o0, o1);
    }
    *(uint4*)(O0out + off) = make_uint4(res[0], res[1], res[2], res[3]);
}

extern "C" void kernel_launch(void* const* d_in, const int* in_sizes, int n_in,
                              void* d_out, int out_size, void* d_ws, size_t ws_size,
                              hipStream_t stream) {
    const float* x    = (const float*)d_in[0];
    const float* Wqkv = (const float*)d_in[1];
    const float* Wo_w = (const float*)d_in[2];
    const float* Wo_b = (const float*)d_in[3];
    float* out = (float*)d_out;

    const size_t MB = 1ull << 20;
    char* ws = (char*)d_ws;
    bf16* xb    = (bf16*)(ws);               // 16 MB; reused as attn O0/final
    bf16* wqkvb = (bf16*)(ws + 16 * MB);     // 6 MB (dead after GEMM1; mlb reuses)
    bf16* wob   = (bf16*)(ws + 22 * MB);     // 2 MB
    bf16* qkv   = (bf16*)(ws + 24 * MB);     // 48 MB
    bf16* Opart1 = (bf16*)(ws + 72 * MB);    // 16 MB
    float2* mlb  = (float2*)(ws + 16 * MB);  // 2 MB over dead wqkvb
    bf16* attnb = xb;

    cast_all<<<12288, 256, 0, stream>>>(x, Wqkv, Wo_w, xb, wqkvb, wob);

    // qkv = x @ Wqkv^T : 128^2 tiles, grid 24*64 = 1536
    gemm_bt<true><<<dim3(TD / 128, Mrows / 128), 256, 0, stream>>>(
        xb, wqkvb, qkv, nullptr, nullptr, Mrows, TD, Dd);

    // attention: 16 heavy halves + 8 light strips per bh = 1536 blocks
    attn_fwd10<<<dim3(Bb * Hh, 24), 256, 0, stream>>>(qkv, attnb, Opart1, mlb);
    attn_combine<<<Bb * 1024 * 128 / 256, 256, 0, stream>>>(Opart1, mlb, attnb);

    // out = attn @ Wo^T + b : grid 8*64 = 512
    gemm_bt<false><<<dim3(Dd / 128, Mrows / 128), 256, 0, stream>>>(
        attnb, wob, nullptr, out, Wo_b, Mrows, Dd, Dd);
}

// Round 19
// 143.758 us; speedup vs baseline: 1.0452x; 1.0452x over previous
//
#include <hip/hip_runtime.h>
#include <hip/hip_bf16.h>

using bf16 = __hip_bfloat16;
typedef __attribute__((ext_vector_type(8))) short bf16x8;
typedef __attribute__((ext_vector_type(4))) short bf16x4;
typedef __attribute__((ext_vector_type(4))) float f32x4;
typedef __attribute__((ext_vector_type(16))) float f32x16;

static constexpr int Bb = 4, Ss = 2048, Dd = 1024, Hh = 16, HD = 64;
static constexpr int TD = 3 * Dd;            // 3072
static constexpr int Mrows = Bb * Ss;        // 8192

#define MFMA16(a, b, c) __builtin_amdgcn_mfma_f32_16x16x32_bf16((a), (b), (c), 0, 0, 0)
#define MFMA32(a, b, c) __builtin_amdgcn_mfma_f32_32x32x16_bf16((a), (b), (c), 0, 0, 0)

__device__ __forceinline__ void gload_lds16(const void* g, void* l) {
    __builtin_amdgcn_global_load_lds(
        (const __attribute__((address_space(1))) void*)g,
        (__attribute__((address_space(3))) void*)l, 16, 0, 0);
}

__device__ __forceinline__ unsigned lds_addr(const void* p) {
    return (unsigned)(unsigned long long)(const __attribute__((address_space(3))) char*)p;
}

__device__ __forceinline__ unsigned pack2bf(float a, float b) {
    bf16 x = __float2bfloat16(a), y = __float2bfloat16(b);
    return (unsigned)(*(unsigned short*)&x) | ((unsigned)(*(unsigned short*)&y) << 16);
}

// ---------------- fused cast fp32 -> bf16 (x, Wqkv, Wo in one launch) ------
__global__ void cast_all(const float* __restrict__ x, const float* __restrict__ w1,
                         const float* __restrict__ w2, bf16* __restrict__ xb,
                         bf16* __restrict__ w1b, bf16* __restrict__ w2b) {
    int i = blockIdx.x * blockDim.x + threadIdx.x;   // 4-elem groups
    const float* src; bf16* dst; int off;
    if (i < 2097152)      { src = x;  dst = xb;  off = i; }
    else if (i < 2883584) { src = w1; dst = w1b; off = i - 2097152; }
    else                  { src = w2; dst = w2b; off = i - 2883584; }
    float4 v = ((const float4*)src)[off];
    uint2 o;
    o.x = pack2bf(v.x, v.y);
    o.y = pack2bf(v.z, v.w);
    *(uint2*)(dst + 4l * off) = o;
}

// ---------------- GEMM: C[m,n] = sum_k A[m,k] * Bt[n,k] ----------------
// r14 proven win: 128x128 tile, BK=64, XOR-swizzled LDS (128B rows),
// simple 2-barrier loop, 32KB LDS, (256,4). Fragment reads 2-way max
// (free, m136); conflicts 6.3M -> ~0; TLP at 4-5 blocks/CU hides staging.
template<bool OUT_BF16>
__global__ __launch_bounds__(256, 4) void gemm_bt(
    const bf16* __restrict__ A, const bf16* __restrict__ Bt,
    bf16* __restrict__ Cb, float* __restrict__ Cf, const float* __restrict__ bias,
    int M, int N, int K)
{
    __shared__ __align__(16) bf16 As[128 * 64];   // 16 KB
    __shared__ __align__(16) bf16 Bs[128 * 64];   // 16 KB
    const int tid = threadIdx.x;
    const int lane = tid & 63, wid = tid >> 6;
    const int lc = lane & 15, lg = lane >> 4;
    const int wr = wid >> 1, wc = wid & 1;

    const int nwg = gridDim.x * gridDim.y;
    int orig = blockIdx.y * gridDim.x + blockIdx.x;
    int swz = orig;
    if ((nwg & 7) == 0) swz = (orig & 7) * (nwg >> 3) + (orig >> 3);
    const long tile_m = (long)(swz / (int)gridDim.x) * 128;
    const long tile_n = (long)(swz % (int)gridDim.x) * 128;

    const f32x4 fz = {0.f, 0.f, 0.f, 0.f};
    f32x4 acc[4][4];
#pragma unroll
    for (int i = 0; i < 4; ++i)
#pragma unroll
        for (int j = 0; j < 4; ++j) acc[i][j] = fz;

    for (int k0 = 0; k0 < K; k0 += 64) {
#pragma unroll
        for (int it = 0; it < 4; ++it) {
            int s = tid + it * 256;
            int r = s >> 3;
            int cs = (s & 7) ^ (r & 7);
            gload_lds16(A  + (tile_m + r) * (long)K + k0 + cs * 8, (char*)As + s * 16);
            gload_lds16(Bt + (tile_n + r) * (long)K + k0 + cs * 8, (char*)Bs + s * 16);
        }
        __syncthreads();
#pragma unroll
        for (int ks = 0; ks < 2; ++ks) {
            bf16x8 af[4], bfr[4];
#pragma unroll
            for (int i = 0; i < 4; ++i) {
                int rowa = wr * 64 + i * 16 + lc;
                af[i] = *(const bf16x8*)((const char*)As +
                        ((rowa * 128 + ks * 64 + lg * 16) ^ ((rowa & 7) << 4)));
                int rowb = wc * 64 + i * 16 + lc;
                bfr[i] = *(const bf16x8*)((const char*)Bs +
                        ((rowb * 128 + ks * 64 + lg * 16) ^ ((rowb & 7) << 4)));
            }
#pragma unroll
            for (int i = 0; i < 4; ++i)
#pragma unroll
                for (int j = 0; j < 4; ++j)
                    acc[i][j] = MFMA16(af[i], bfr[j], acc[i][j]);
        }
        __syncthreads();
    }
#pragma unroll
    for (int i = 0; i < 4; ++i)
#pragma unroll
        for (int j = 0; j < 4; ++j)
#pragma unroll
            for (int r = 0; r < 4; ++r) {
                long row = tile_m + wr * 64 + i * 16 + lg * 4 + r;
                long col = tile_n + wc * 64 + j * 16 + lc;
                float v = acc[i][j][r];
                if constexpr (OUT_BF16) Cb[row * N + col] = __float2bfloat16(v);
                else                    Cf[row * N + col] = v + bias[col];
            }
}

// ---------------- causal flash attention v8 (measured best: 68.4us) --------
// 2-buffer dbuf, heavy-first strips, single strip/block. Softmax VALU diet:
// v_cvt_pk_bf16_f32 pack, depth-5 tree max, 4-way partial sums, literal
// tr-read offsets. Swapped QK^T (32x32 MFMA), in-register softmax,
// permlane32_swap P-exchange, ds_read_b64_tr_b16 V reads, defer-max.
__global__ __launch_bounds__(256, 2) void attn_fwd8(const bf16* __restrict__ qkv,
                                                    bf16* __restrict__ out) {
    const int bh = blockIdx.x;                 // 0..63
    const int p  = blockIdx.y;                 // 0..15
    const int s  = 15 - p;                     // strip index, heavy first
    const int b = bh >> 4, h = bh & 15;
    const int tid = threadIdx.x;
    const int lane = tid & 63, wid = tid >> 6;
    const int ln31 = lane & 31, hi = lane >> 5;
    const int ch = (lane >> 4) & 1, c16 = lane & 15;
    const long rowbase = (long)b * Ss;
    const int q0 = s * 128 + wid * 32;         // this wave's 32 q-rows
    const int nt = 2 * s + 2;                  // causal kv tiles
    const float CL2 = 0.18033688f;             // 0.125 * log2(e)

    __shared__ __align__(16) bf16 Ks[2][64 * 64];
    __shared__ __align__(16) bf16 Vs[2][64 * 64];

    const int sK0 = tid, sK1 = tid + 256;
    const int rK0 = sK0 >> 3, cK0 = ((sK0 & 7) ^ (rK0 & 7)) * 8;
    const int rK1 = sK1 >> 3, cK1 = ((sK1 & 7) ^ (rK1 & 7)) * 8;
    const int rV0 = ((sK0 >> 5) << 2) | ((sK0 >> 1) & 3);
    const int cV0 = ((((sK0 >> 3) & 3) << 1) | (sK0 & 1)) * 8;
    const int rV1 = ((sK1 >> 5) << 2) | ((sK1 >> 1) & 3);
    const int cV1 = ((((sK1 >> 3) & 3) << 1) | (sK1 & 1)) * 8;
    const bf16* gK0 = qkv + (rowbase + rK0) * (long)TD + h * HD + Dd + cK0;
    const bf16* gK1 = qkv + (rowbase + rK1) * (long)TD + h * HD + Dd + cK1;
    const bf16* gV0 = qkv + (rowbase + rV0) * (long)TD + h * HD + 2 * Dd + cV0;
    const bf16* gV1 = qkv + (rowbase + rV1) * (long)TD + h * HD + 2 * Dd + cV1;

    auto STAGE = [&](int buf, int kt) {
        const long o = (long)kt * 64 * TD;
        gload_lds16(gK0 + o, (char*)Ks[buf] + tid * 16);
        gload_lds16(gK1 + o, (char*)Ks[buf] + 4096 + tid * 16);
        gload_lds16(gV0 + o, (char*)Vs[buf] + tid * 16);
        gload_lds16(gV1 + o, (char*)Vs[buf] + 4096 + tid * 16);
    };

    bf16x8 qa[4];
#pragma unroll
    for (int dk = 0; dk < 4; ++dk)
        qa[dk] = *(const bf16x8*)(qkv + (rowbase + q0 + ln31) * (long)TD + h * HD + dk * 16 + hi * 8);

    f32x16 acc[2];
#pragma unroll
    for (int dt = 0; dt < 2; ++dt) acc[dt] = (f32x16)0.0f;
    float m2 = -3.0e38f;
    float l = 0.f;

    STAGE(0, 0);
    __syncthreads();

    for (int kt = 0; kt < nt; ++kt) {
        const int cur = kt & 1;
        if (kt + 1 < nt) STAGE(cur ^ 1, kt + 1);

        if (kt * 64 <= q0 + 31) {
            const char* kbp = (const char*)Ks[cur];
            const char* vbp = (const char*)Vs[cur];
            f32x16 sc[2];
            __builtin_amdgcn_s_setprio(1);
#pragma unroll
            for (int st = 0; st < 2; ++st) {
                f32x16 z = (f32x16)0.0f;
                const int row = st * 32 + ln31;
                const int sw = (row & 7) << 4;
#pragma unroll
                for (int dk = 0; dk < 4; ++dk) {
                    bf16x8 ka = *(const bf16x8*)(kbp + ((row * 128 + dk * 32 + hi * 16) ^ sw));
                    z = MFMA32(ka, qa[dk], z);
                }
                sc[st] = z;
            }
            __builtin_amdgcn_s_setprio(0);
            if (kt * 64 + 63 > q0) {
                const int qg = q0 + ln31;
                const int kbase = kt * 64 + 4 * hi;
#pragma unroll
                for (int st = 0; st < 2; ++st)
#pragma unroll
                    for (int r = 0; r < 16; ++r) {
                        int kg = kbase + st * 32 + (r & 3) + 8 * (r >> 2);
                        if (kg > qg) sc[st][r] = -3.0e38f;
                    }
            }
            // ---- row max: depth-5 pairwise tree ----
            float mt16[16];
#pragma unroll
            for (int r = 0; r < 16; ++r) mt16[r] = fmaxf(sc[0][r], sc[1][r]);
#pragma unroll
            for (int off = 8; off; off >>= 1)
#pragma unroll
                for (int r = 0; r < off; ++r) mt16[r] = fmaxf(mt16[r], mt16[r + off]);
            float mx = fmaxf(mt16[0], __shfl_xor(mt16[0], 32));
            float pmax2 = mx * CL2;
            // ---- defer-max rescale (rare) ----
            if (__ballot(pmax2 > m2 + 8.0f)) {
                float mnew = fmaxf(m2, pmax2);
                float sf = __builtin_amdgcn_exp2f(m2 - mnew);
                m2 = mnew;
                l *= sf;
#pragma unroll
                for (int r = 0; r < 16; ++r) {
                    float sfr = __shfl(sf, (r & 3) + 8 * (r >> 2) + 4 * hi);
                    acc[0][r] *= sfr;
                    acc[1][r] *= sfr;
                }
            }
            // ---- issue all 16 V tr-reads early (literal offsets, 1 base) ----
            bf16x4 vl[4][2], vh[4][2];
            const unsigned vbase = lds_addr(vbp) + hi * 1024 + ch * 128 + c16 * 8;
#define TRRD(L, H, O1, O2) \
            asm volatile("ds_read_b64_tr_b16 %0, %2 offset:" O1 "\n\t" \
                         "ds_read_b64_tr_b16 %1, %2 offset:" O2 \
                         : "=v"(L), "=v"(H) : "v"(vbase) : "memory");
            TRRD(vl[0][0], vh[0][0], "0",    "512")
            TRRD(vl[0][1], vh[0][1], "256",  "768")
            TRRD(vl[1][0], vh[1][0], "2048", "2560")
            TRRD(vl[1][1], vh[1][1], "2304", "2816")
            TRRD(vl[2][0], vh[2][0], "4096", "4608")
            TRRD(vl[2][1], vh[2][1], "4352", "4864")
            TRRD(vl[3][0], vh[3][0], "6144", "6656")
            TRRD(vl[3][1], vh[3][1], "6400", "6912")
#undef TRRD
            // ---- exp + 4-way partial sums + hw cvt_pk pack ----
            const float mt = m2;
            float s4[4] = {0.f, 0.f, 0.f, 0.f};
            unsigned w[2][8];
#pragma unroll
            for (int st = 0; st < 2; ++st)
#pragma unroll
                for (int n = 0; n < 8; ++n) {
                    float e0 = __builtin_amdgcn_exp2f(fmaf(sc[st][2 * n],     CL2, -mt));
                    float e1 = __builtin_amdgcn_exp2f(fmaf(sc[st][2 * n + 1], CL2, -mt));
                    s4[n & 3] += e0 + e1;
                    asm("v_cvt_pk_bf16_f32 %0, %1, %2"
                        : "=v"(w[st][n]) : "v"(e0), "v"(e1));
                }
            float sum = (s4[0] + s4[1]) + (s4[2] + s4[3]);
            sum += __shfl_xor(sum, 32);
            l += sum;
            // ---- P exchange: 8 permlane32_swap ----
            union { unsigned u[4]; bf16x8 v; } pa[4];
#pragma unroll
            for (int ksg = 0; ksg < 4; ++ksg) {
                const int st = ksg >> 1, kl = ksg & 1;
                unsigned x0 = w[st][4 * kl],     y0 = w[st][4 * kl + 2];
                unsigned x1 = w[st][4 * kl + 1], y1 = w[st][4 * kl + 3];
                asm volatile("v_permlane32_swap_b32 %0, %1" : "+v"(x0), "+v"(y0));
                asm volatile("v_permlane32_swap_b32 %0, %1" : "+v"(x1), "+v"(y1));
                pa[ksg].u[0] = x0; pa[ksg].u[1] = x1; pa[ksg].u[2] = y0; pa[ksg].u[3] = y1;
            }
            // ---- PV ----
            asm volatile("s_waitcnt lgkmcnt(0)" ::: "memory");
            __builtin_amdgcn_sched_barrier(0);
            __builtin_amdgcn_s_setprio(1);
#pragma unroll
            for (int ksg = 0; ksg < 4; ++ksg)
#pragma unroll
                for (int dt = 0; dt < 2; ++dt) {
                    bf16x8 vb = __builtin_shufflevector(vl[ksg][dt], vh[ksg][dt],
                                                        0, 1, 2, 3, 4, 5, 6, 7);
                    acc[dt] = MFMA32(pa[ksg].v, vb, acc[dt]);
                }
            __builtin_amdgcn_s_setprio(0);
        }

        __syncthreads();
    }

    float invl = 1.f / l;
#pragma unroll
    for (int r = 0; r < 16; ++r) {
        float ir = __shfl(invl, (r & 3) + 8 * (r >> 2) + 4 * hi);
        long orow = rowbase + q0 + (r & 3) + 8 * (r >> 2) + 4 * hi;
#pragma unroll
        for (int dt = 0; dt < 2; ++dt)
            out[orow * Dd + h * HD + dt * 32 + ln31] = __float2bfloat16(acc[dt][r] * ir);
    }
}

extern "C" void kernel_launch(void* const* d_in, const int* in_sizes, int n_in,
                              void* d_out, int out_size, void* d_ws, size_t ws_size,
                              hipStream_t stream) {
    const float* x    = (const float*)d_in[0];
    const float* Wqkv = (const float*)d_in[1];
    const float* Wo_w = (const float*)d_in[2];
    const float* Wo_b = (const float*)d_in[3];
    float* out = (float*)d_out;

    const size_t MB = 1ull << 20;
    char* ws = (char*)d_ws;
    bf16* xb    = (bf16*)(ws);               // 16 MB; reused as attn output
    bf16* wqkvb = (bf16*)(ws + 16 * MB);     // 6 MB
    bf16* wob   = (bf16*)(ws + 22 * MB);     // 2 MB
    bf16* qkv   = (bf16*)(ws + 24 * MB);     // 48 MB
    bf16* attnb = xb;

    cast_all<<<12288, 256, 0, stream>>>(x, Wqkv, Wo_w, xb, wqkvb, wob);

    // qkv = x @ Wqkv^T : 128^2 tiles, grid 24*64 = 1536
    gemm_bt<true><<<dim3(TD / 128, Mrows / 128), 256, 0, stream>>>(
        xb, wqkvb, qkv, nullptr, nullptr, Mrows, TD, Dd);

    attn_fwd8<<<dim3(Bb * Hh, 16), 256, 0, stream>>>(qkv, attnb);

    // out = attn @ Wo^T + b : grid 8*64 = 512
    gemm_bt<false><<<dim3(Dd / 128, Mrows / 128), 256, 0, stream>>>(
        attnb, wob, nullptr, out, Wo_b, Mrows, Dd, Dd);
}